// Round 9
// baseline (374.129 us; speedup 1.0000x reference)
//
#include <hip/hip_runtime.h>
#include <hip/hip_bf16.h>
#include <math.h>

// Problem constants
#define B_   16
#define IC_  32
#define HW_  128
#define NF_  8
#define OC_  64
#define K_   5
#define GRP_ 8
#define COTOT_ (OC_ * GRP_)   // 512
#define XTH  132              // padded spatial (128 + 2*2)
#define TAPSTRIDE (COTOT_ * IC_)   // elements per tap in wt
#define XROWB (XTH * IC_ * 2)      // 8448 bytes per xs row

typedef short  short8  __attribute__((ext_vector_type(8)));
typedef unsigned short ushort8 __attribute__((ext_vector_type(8)));
typedef float  f32x4   __attribute__((ext_vector_type(4)));

static __device__ inline unsigned short f2bf(float f) {
    unsigned u = __builtin_bit_cast(unsigned, f);
    unsigned r = (u + 0x7FFFu + ((u >> 16) & 1u)) >> 16;
    return (unsigned short)r;
}

// async global -> LDS, 16 bytes per lane (dest = uniform base + lane*16)
__device__ __forceinline__ void gload16(void* lds, const void* g) {
    __builtin_amdgcn_global_load_lds(
        (const __attribute__((address_space(1))) unsigned int*)g,
        (__attribute__((address_space(3))) unsigned int*)lds, 16, 0, 0);
}

// ---------------------------------------------------------------------------
// Kernel 1: x NCHW fp32 -> padded NHWC bf16   xt[b][hp][wp][ic]
// ---------------------------------------------------------------------------
__global__ __launch_bounds__(256) void xform_kernel(
    const float* __restrict__ x, unsigned short* __restrict__ xt) {
    int idx = blockIdx.x * blockDim.x + threadIdx.x;
    const int TOT = B_ * XTH * XTH;
    if (idx >= TOT) return;
    int wp = idx % XTH;
    int t  = idx / XTH;
    int hp = t % XTH;
    int b  = t / XTH;

    unsigned short vals[IC_];
    bool interior = (hp >= 2) && (hp < 2 + HW_) && (wp >= 2) && (wp < 2 + HW_);
    if (interior) {
        const float* xb = x + ((size_t)b * IC_) * (HW_ * HW_) + (hp - 2) * HW_ + (wp - 2);
        #pragma unroll
        for (int ic = 0; ic < IC_; ++ic)
            vals[ic] = f2bf(xb[(size_t)ic * (HW_ * HW_)]);
    } else {
        #pragma unroll
        for (int ic = 0; ic < IC_; ++ic) vals[ic] = 0;
    }
    ushort8* dst = (ushort8*)(xt + (size_t)idx * IC_);
    #pragma unroll
    for (int c = 0; c < 4; ++c) {
        ushort8 v;
        #pragma unroll
        for (int j = 0; j < 8; ++j) v[j] = vals[c * 8 + j];
        dst[c] = v;
    }
}

// ---------------------------------------------------------------------------
// Kernel 2: rotated+mixed weights -> bf16, layout wt[tap25][co512][ic32]
// ---------------------------------------------------------------------------
__global__ __launch_bounds__(256) void build_w_kernel(
    const float* __restrict__ kern,
    const float* __restrict__ relaxed,
    unsigned short* __restrict__ wt) {
    int idx = blockIdx.x * blockDim.x + threadIdx.x;
    const int TOT = 25 * COTOT_ * IC_;
    if (idx >= TOT) return;
    int ic = idx & (IC_ - 1);
    int t  = idx >> 5;
    int co = t & (COTOT_ - 1);
    int e  = t >> 9;            // ky*5+kx
    int a  = co & (GRP_ - 1);
    int o  = co >> 3;
    int i  = e / K_;            // ky
    int j  = e - i * K_;        // kx

    float theta = -6.283185307179586f / (float)GRP_ * (float)a;
    float cth = cosf(theta), sth = sinf(theta);
    float bx = (2.0f * (float)j + 1.0f) / (float)K_ - 1.0f;
    float by = (2.0f * (float)i + 1.0f) / (float)K_ - 1.0f;
    float gx = cth * bx - sth * by;
    float gy = sth * bx + cth * by;
    float ix = ((gx + 1.0f) * (float)K_ - 1.0f) * 0.5f;
    float iy = ((gy + 1.0f) * (float)K_ - 1.0f) * 0.5f;
    float x0 = floorf(ix), y0 = floorf(iy);
    float wx1 = ix - x0, wy1 = iy - y0;
    float wx0 = 1.0f - wx1, wy0 = 1.0f - wy1;

    float xs2[2]  = {x0, x0 + 1.0f};
    float ys2[2]  = {y0, y0 + 1.0f};
    float wxs[2] = {wx0, wx1};
    float wys[2] = {wy0, wy1};

    float tw[4];
    int   tyc[4], txc[4];
    #pragma unroll
    for (int dy = 0; dy < 2; ++dy) {
        #pragma unroll
        for (int dx = 0; dx < 2; ++dx) {
            float xx = xs2[dx], yy = ys2[dy];
            bool valid = (xx >= 0.0f) && (xx < (float)K_) &&
                         (yy >= 0.0f) && (yy < (float)K_);
            int tp = dy * 2 + dx;
            tw[tp]  = wys[dy] * wxs[dx] * (valid ? 1.0f : 0.0f);
            txc[tp] = (int)fminf(fmaxf(xx, 0.0f), (float)(K_ - 1));
            tyc[tp] = (int)fminf(fmaxf(yy, 0.0f), (float)(K_ - 1));
        }
    }

    float acc = 0.0f;
    #pragma unroll
    for (int n = 0; n < NF_; ++n) {
        const float* kb = kern + ((size_t)((n * OC_ + o) * IC_ + ic)) * (K_ * K_);
        float v = 0.0f;
        #pragma unroll
        for (int tp = 0; tp < 4; ++tp)
            v += kb[tyc[tp] * K_ + txc[tp]] * tw[tp];
        acc += relaxed[n * GRP_ + a] * v;
    }
    wt[idx] = f2bf(acc);
}

// ---------------------------------------------------------------------------
// Kernel 3: MFMA implicit-GEMM conv + leaky relu (8-phase-style schedule)
// block = 512 thr (8 waves) = 256 co x 2 h x 128 w; 1 block/CU, 2 waves/SIMD
// wave  = 128 co x 64 w at one h row (8x4 frags), 16-MFMA phases
// A: LDS ring (3 x 16 KB), staged 2 taps ahead via global_load_lds,
//    counted vmcnt(2) once per tap (never 0 in the loop) [T3+T4]
// per tap: 2 phases {ds_read || gload-issue -> s_barrier -> lgkmcnt(0)
//          -> setprio(1) -> 16 MFMA -> setprio(0) -> s_barrier}  [T5]
// xs slab + A slices chunk-XOR-swizzled (verified R6-R8) -> 2-way banks.
// ---------------------------------------------------------------------------
__global__ __launch_bounds__(512, 2) void conv_mfma_kernel(
    const unsigned short* __restrict__ xt,
    const unsigned short* __restrict__ wt,
    float* __restrict__ out) {
    __shared__ __align__(16) unsigned short xs[6 * XTH * IC_];   // 50688 B
    __shared__ __align__(16) unsigned short wring[3][8192];      // 3 x 16384 B

    int tid  = threadIdx.x;
    int lane = tid & 63;
    int wid  = tid >> 6;          // 0..7
    int l15  = lane & 15;
    int l4   = lane >> 4;         // k-chunk
    int wr   = wid >> 2;          // co half (0/1)
    int wc   = wid & 3;
    int hr   = wc >> 1;           // h row (0/1)
    int wq   = wc & 1;            // w half (0/1)

    int hp = blockIdx.x;          // 0..63 -> rows 2*hp, 2*hp+1
    int b  = blockIdx.y;
    int cg = blockIdx.z;          // 0..1, slowest
    int cobase = cg * 256;
    int h0 = hp * 2;

    // ---- stage x slab rows h0..h0+5 (linear dest, swizzled source) ----
    {
        const unsigned short* xb = xt + (((size_t)b * XTH + h0) * XTH) * IC_;
        #pragma unroll
        for (int i = 0; i < 7; ++i) {
            int s = i * 512 + tid;          // 16B slots, 3168 total
            if (s < 3168) {
                int row = s / 528;
                int rem = s - row * 528;
                int w   = rem >> 2;
                int p   = rem & 3;
                int c   = p ^ ((w >> 1) & 3);
                gload16(&xs[s * 8], xb + row * (XTH * IC_) + w * 32 + c * 8);
            }
        }
    }
    // ---- stage A for taps 0,1 into ring 0,1 (slice [co256][chunk4], swz) ----
    {
        #pragma unroll
        for (int tp = 0; tp < 2; ++tp) {
            #pragma unroll
            for (int i = 0; i < 2; ++i) {
                int s  = i * 512 + tid;     // 1024 slots
                int co = s >> 2;
                int c  = (s & 3) ^ ((s >> 3) & 3);
                gload16(&wring[tp][s * 8],
                        wt + (size_t)tp * TAPSTRIDE + (size_t)(cobase + co) * IC_ + c * 8);
            }
        }
    }

    f32x4 acc[8][4];
    #pragma unroll
    for (int m = 0; m < 8; ++m)
        #pragma unroll
        for (int n = 0; n < 4; ++n) acc[m][n] = (f32x4)(0.0f);

    asm volatile("s_waitcnt vmcnt(0)" ::: "memory");
    __builtin_amdgcn_s_barrier();

    const char* xsb = (const char*)xs;
    const int awz = (l4 ^ ((l15 & 7) >> 1)) << 4;   // A-read chunk swizzle
    const int abase = (wr * 128 + l15) * 64 + awz;  // + m*1024
    int rowoff = hr * XROWB;
    int kx = 0;
    int rcur = 0, rst = 2;

    #pragma unroll 1
    for (int t = 0; t < 25; ++t) {
        const char* wb = (const char*)wring[rcur];

        // ================= phase 0 =================
        if (t < 23) {   // stage slot 0 of tap t+2
            int s  = tid;
            int co = s >> 2;
            int c  = (s & 3) ^ ((s >> 3) & 3);
            gload16(&wring[rst][s * 8],
                    wt + (size_t)(t + 2) * TAPSTRIDE + (size_t)(cobase + co) * IC_ + c * 8);
        }
        short8 af03[4];
        #pragma unroll
        for (int m = 0; m < 4; ++m)
            af03[m] = *(const short8*)(wb + abase + m * 1024);
        int bbase = rowoff + (wq * 64 + kx + l15) * 64 +
                    ((l4 ^ (((kx + l15) & 7) >> 1)) << 4);
        short8 bf[4];
        #pragma unroll
        for (int n = 0; n < 4; ++n)
            bf[n] = *(const short8*)(xsb + bbase + n * 1024);

        __builtin_amdgcn_s_barrier();
        asm volatile("s_waitcnt lgkmcnt(0)" ::: "memory");
        __builtin_amdgcn_s_setprio(1);
        #pragma unroll
        for (int m = 0; m < 4; ++m)
            #pragma unroll
            for (int n = 0; n < 4; ++n)
                acc[m][n] = __builtin_amdgcn_mfma_f32_16x16x32_bf16(
                    af03[m], bf[n], acc[m][n], 0, 0, 0);
        __builtin_amdgcn_s_setprio(0);
        __builtin_amdgcn_s_barrier();

        // ================= phase 1 =================
        if (t < 23) {   // stage slot 1 of tap t+2
            int s  = 512 + tid;
            int co = s >> 2;
            int c  = (s & 3) ^ ((s >> 3) & 3);
            gload16(&wring[rst][s * 8],
                    wt + (size_t)(t + 2) * TAPSTRIDE + (size_t)(cobase + co) * IC_ + c * 8);
        }
        short8 af47[4];
        #pragma unroll
        for (int m = 0; m < 4; ++m)
            af47[m] = *(const short8*)(wb + abase + (m + 4) * 1024);

        __builtin_amdgcn_s_barrier();
        asm volatile("s_waitcnt lgkmcnt(0)" ::: "memory");
        __builtin_amdgcn_s_setprio(1);
        #pragma unroll
        for (int m = 0; m < 4; ++m)
            #pragma unroll
            for (int n = 0; n < 4; ++n)
                acc[m + 4][n] = __builtin_amdgcn_mfma_f32_16x16x32_bf16(
                    af47[m], bf[n], acc[m + 4][n], 0, 0, 0);
        __builtin_amdgcn_s_setprio(0);

        // retire everything except the 2 newest (tap t+2's) -> tap t+1 resident
        if (t < 23)       asm volatile("s_waitcnt vmcnt(2)" ::: "memory");
        else if (t == 23) asm volatile("s_waitcnt vmcnt(0)" ::: "memory");
        __builtin_amdgcn_s_barrier();

        if (++kx == 5) { kx = 0; rowoff += XROWB; }
        if (++rcur == 3) rcur = 0;
        if (++rst == 3) rst = 0;
    }

    // ---- epilogue: leaky relu + store ----
    int h = h0 + hr;
    float* ob = out + ((size_t)b * COTOT_ + cobase + wr * 128) * (HW_ * HW_)
                    + (size_t)h * HW_ + wq * 64;
    #pragma unroll
    for (int m = 0; m < 8; ++m) {
        #pragma unroll
        for (int n = 0; n < 4; ++n) {
            #pragma unroll
            for (int r = 0; r < 4; ++r) {
                int co = m * 16 + l4 * 4 + r;
                int w  = n * 16 + l15;
                float v = acc[m][n][r];
                v = (v >= 0.0f) ? v : 0.01f * v;
                ob[(size_t)co * (HW_ * HW_) + w] = v;
            }
        }
    }
}

extern "C" void kernel_launch(void* const* d_in, const int* in_sizes, int n_in,
                              void* d_out, int out_size, void* d_ws, size_t ws_size,
                              hipStream_t stream) {
    const float* x       = (const float*)d_in[0];
    const float* kernel  = (const float*)d_in[1];
    const float* relaxed = (const float*)d_in[2];
    float* out = (float*)d_out;

    unsigned short* xt = (unsigned short*)d_ws;   // 16*132*132*32*2 = 17,842,176 B
    unsigned short* wt = (unsigned short*)((char*)d_ws + (size_t)B_ * XTH * XTH * IC_ * 2);

    const int xtot = B_ * XTH * XTH;
    xform_kernel<<<(xtot + 255) / 256, 256, 0, stream>>>(x, xt);

    const int wtot = 25 * COTOT_ * IC_;
    build_w_kernel<<<(wtot + 255) / 256, 256, 0, stream>>>(kernel, relaxed, wt);

    dim3 grid(HW_ / 2, B_, COTOT_ / 256);
    conv_mfma_kernel<<<grid, 512, 0, stream>>>(xt, wt, out);
}

// Round 10
// 307.113 us; speedup vs baseline: 1.2182x; 1.2182x over previous
//
#include <hip/hip_runtime.h>
#include <hip/hip_bf16.h>
#include <math.h>

// Problem constants
#define B_   16
#define IC_  32
#define HW_  128
#define NF_  8
#define OC_  64
#define K_   5
#define GRP_ 8
#define COTOT_ (OC_ * GRP_)   // 512
#define XTH  132              // padded spatial (128 + 2*2)
#define TAPSTRIDE (COTOT_ * IC_)   // elements per tap in wt
#define XROWB (XTH * IC_ * 2)      // 8448 bytes per xs row
#define HW2  (HW_ * HW_)

typedef short  short8  __attribute__((ext_vector_type(8)));
typedef unsigned short ushort8 __attribute__((ext_vector_type(8)));
typedef float  f32x16  __attribute__((ext_vector_type(16)));

static __device__ inline unsigned short f2bf(float f) {
    unsigned u = __builtin_bit_cast(unsigned, f);
    unsigned r = (u + 0x7FFFu + ((u >> 16) & 1u)) >> 16;
    return (unsigned short)r;
}

// async global -> LDS, 16 bytes per lane (dest = uniform base + lane*16)
__device__ __forceinline__ void gload16(void* lds, const void* g) {
    __builtin_amdgcn_global_load_lds(
        (const __attribute__((address_space(1))) unsigned int*)g,
        (__attribute__((address_space(3))) unsigned int*)lds, 16, 0, 0);
}

// ---------------------------------------------------------------------------
// Kernel 1: x NCHW fp32 -> padded NHWC bf16   xt[b][hp][wp][ic]
// ---------------------------------------------------------------------------
__global__ __launch_bounds__(256) void xform_kernel(
    const float* __restrict__ x, unsigned short* __restrict__ xt) {
    int idx = blockIdx.x * blockDim.x + threadIdx.x;
    const int TOT = B_ * XTH * XTH;
    if (idx >= TOT) return;
    int wp = idx % XTH;
    int t  = idx / XTH;
    int hp = t % XTH;
    int b  = t / XTH;

    unsigned short vals[IC_];
    bool interior = (hp >= 2) && (hp < 2 + HW_) && (wp >= 2) && (wp < 2 + HW_);
    if (interior) {
        const float* xb = x + ((size_t)b * IC_) * HW2 + (hp - 2) * HW_ + (wp - 2);
        #pragma unroll
        for (int ic = 0; ic < IC_; ++ic)
            vals[ic] = f2bf(xb[(size_t)ic * HW2]);
    } else {
        #pragma unroll
        for (int ic = 0; ic < IC_; ++ic) vals[ic] = 0;
    }
    ushort8* dst = (ushort8*)(xt + (size_t)idx * IC_);
    #pragma unroll
    for (int c = 0; c < 4; ++c) {
        ushort8 v;
        #pragma unroll
        for (int j = 0; j < 8; ++j) v[j] = vals[c * 8 + j];
        dst[c] = v;
    }
}

// ---------------------------------------------------------------------------
// Kernel 2: rotated+mixed weights -> bf16, layout wt[tap25][co512][ic32]
// ---------------------------------------------------------------------------
__global__ __launch_bounds__(256) void build_w_kernel(
    const float* __restrict__ kern,
    const float* __restrict__ relaxed,
    unsigned short* __restrict__ wt) {
    int idx = blockIdx.x * blockDim.x + threadIdx.x;
    const int TOT = 25 * COTOT_ * IC_;
    if (idx >= TOT) return;
    int ic = idx & (IC_ - 1);
    int t  = idx >> 5;
    int co = t & (COTOT_ - 1);
    int e  = t >> 9;            // ky*5+kx
    int a  = co & (GRP_ - 1);
    int o  = co >> 3;
    int i  = e / K_;            // ky
    int j  = e - i * K_;        // kx

    float theta = -6.283185307179586f / (float)GRP_ * (float)a;
    float cth = cosf(theta), sth = sinf(theta);
    float bx = (2.0f * (float)j + 1.0f) / (float)K_ - 1.0f;
    float by = (2.0f * (float)i + 1.0f) / (float)K_ - 1.0f;
    float gx = cth * bx - sth * by;
    float gy = sth * bx + cth * by;
    float ix = ((gx + 1.0f) * (float)K_ - 1.0f) * 0.5f;
    float iy = ((gy + 1.0f) * (float)K_ - 1.0f) * 0.5f;
    float x0 = floorf(ix), y0 = floorf(iy);
    float wx1 = ix - x0, wy1 = iy - y0;
    float wx0 = 1.0f - wx1, wy0 = 1.0f - wy1;

    float xs2[2]  = {x0, x0 + 1.0f};
    float ys2[2]  = {y0, y0 + 1.0f};
    float wxs[2] = {wx0, wx1};
    float wys[2] = {wy0, wy1};

    float tw[4];
    int   tyc[4], txc[4];
    #pragma unroll
    for (int dy = 0; dy < 2; ++dy) {
        #pragma unroll
        for (int dx = 0; dx < 2; ++dx) {
            float xx = xs2[dx], yy = ys2[dy];
            bool valid = (xx >= 0.0f) && (xx < (float)K_) &&
                         (yy >= 0.0f) && (yy < (float)K_);
            int tp = dy * 2 + dx;
            tw[tp]  = wys[dy] * wxs[dx] * (valid ? 1.0f : 0.0f);
            txc[tp] = (int)fminf(fmaxf(xx, 0.0f), (float)(K_ - 1));
            tyc[tp] = (int)fminf(fmaxf(yy, 0.0f), (float)(K_ - 1));
        }
    }

    float acc = 0.0f;
    #pragma unroll
    for (int n = 0; n < NF_; ++n) {
        const float* kb = kern + ((size_t)((n * OC_ + o) * IC_ + ic)) * (K_ * K_);
        float v = 0.0f;
        #pragma unroll
        for (int tp = 0; tp < 4; ++tp)
            v += kb[tyc[tp] * K_ + txc[tp]] * tw[tp];
        acc += relaxed[n * GRP_ + a] * v;
    }
    wt[idx] = f2bf(acc);
}

// ---------------------------------------------------------------------------
// Kernel 3: MFMA implicit-GEMM conv + leaky relu  (32x32x16 MFMA)
// block = 256 thr (4 waves) = 128 co x 4 h x 128 w; 1 block/CU, 1 wave/SIMD
// wave  = 4x4 frags of 32x32: 128 co x 128 w at one h row, acc = 16xf32x16
// 2 slabs per block (grid halved): amortizes prologue, L2-warm weights.
// Weights: global -> VGPR (8 reads of 16B/tap), register double-buffer.
// x: swizzled LDS slab (verified conflict-free R9), reg-dbuf'd bf reads.
// Barrier-free tap loop; 32 fat MFMA/tap halves issue overhead vs 16x16.
// ---------------------------------------------------------------------------
#define PREF_AF(dst, tap) {                                                   \
    const unsigned short* wp_ = wl + (size_t)(tap) * TAPSTRIDE;               \
    _Pragma("unroll")                                                         \
    for (int mf = 0; mf < 4; ++mf)                                            \
        _Pragma("unroll")                                                     \
        for (int kk = 0; kk < 2; ++kk)                                        \
            dst[mf * 2 + kk] = *(const short8*)(wp_ + mf * 1024 + kk * 16);   \
}

#define PREF_BF(dst) {                                                        \
    int sw_ = ((pkx + l31) >> 1) & 3;                                         \
    int wb_ = prow + (pkx + l31) * 64;                                        \
    _Pragma("unroll")                                                         \
    for (int nf = 0; nf < 4; ++nf)                                            \
        _Pragma("unroll")                                                     \
        for (int kk = 0; kk < 2; ++kk) {                                      \
            int p_ = (kk * 2 + lhi) ^ sw_;                                    \
            dst[nf * 2 + kk] = *(const short8*)(xsb + wb_ + nf * 2048 + p_ * 16); \
        }                                                                     \
    if (++pkx == 5) { pkx = 0; prow += XROWB; }                               \
}

#define COMP(afx, bfx) {                                                      \
    __builtin_amdgcn_s_setprio(1);                                            \
    _Pragma("unroll")                                                         \
    for (int mf = 0; mf < 4; ++mf)                                            \
        _Pragma("unroll")                                                     \
        for (int nf = 0; nf < 4; ++nf)                                        \
            _Pragma("unroll")                                                 \
            for (int kk = 0; kk < 2; ++kk)                                    \
                acc[mf][nf] = __builtin_amdgcn_mfma_f32_32x32x16_bf16(        \
                    afx[mf * 2 + kk], bfx[nf * 2 + kk], acc[mf][nf], 0, 0, 0);\
    __builtin_amdgcn_s_setprio(0);                                            \
}

__global__ __launch_bounds__(256, 1) void conv_mfma_kernel(
    const unsigned short* __restrict__ xt,
    const unsigned short* __restrict__ wt,
    float* __restrict__ out) {
    // 8 rows x 132 w x 32 ic bf16 = 67584 B (chunk-swizzled via source)
    __shared__ __align__(16) unsigned short xs[8 * XTH * IC_];

    int tid  = threadIdx.x;
    int lane = tid & 63;
    int wv   = tid >> 6;          // 0..3 = wave's h row within slab
    int l31  = lane & 31;
    int lhi  = lane >> 5;         // 0/1 (k-half within 16-group: +8 ic)

    int hp = blockIdx.x;          // 0..15 -> two slabs of 4 rows
    int b  = blockIdx.y;
    int cg = blockIdx.z;          // 0..3, slowest
    int cobase = cg * 128;

    // per-lane weight base: co = cobase + mf*32 + l31, ic = kk*16 + lhi*8 ..
    const unsigned short* wl = wt + (size_t)(cobase + l31) * IC_ + lhi * 8;
    const char* xsb = (const char*)xs;

    #pragma unroll 1
    for (int s = 0; s < 2; ++s) {
        int h0 = hp * 8 + s * 4;

        if (s) __syncthreads();   // all waves done reading xs (prev slab)

        // ---- stage x slab rows h0..h0+7 (linear dest, swizzled source) ----
        {
            const unsigned short* xb = xt + (((size_t)b * XTH + h0) * XTH) * IC_;
            #pragma unroll
            for (int i = 0; i < 17; ++i) {
                int sl = i * 256 + tid;     // 16B slots, 4224 total
                if (sl < 4224) {
                    int row = sl / 528;
                    int rem = sl - row * 528;
                    int w   = rem >> 2;
                    int p   = rem & 3;
                    int c   = p ^ ((w >> 1) & 3);
                    gload16(&xs[sl * 8], xb + row * (XTH * IC_) + w * 32 + c * 8);
                }
            }
        }

        short8 afA[8], afB[8];
        PREF_AF(afA, 0);          // overlaps x staging

        f32x16 acc[4][4];
        #pragma unroll
        for (int mf = 0; mf < 4; ++mf)
            #pragma unroll
            for (int nf = 0; nf < 4; ++nf) acc[mf][nf] = (f32x16)(0.0f);

        __syncthreads();          // xs ready (drains vmcnt)

        int pkx  = 0;
        int prow = wv * XROWB;

        short8 bfA[8], bfB[8];
        PREF_BF(bfA);             // tap 0

        #pragma unroll 1
        for (int pi = 0; pi < 12; ++pi) {
            int t0 = pi * 2;
            PREF_AF(afB, t0 + 1);
            PREF_BF(bfB);
            COMP(afA, bfA);       // tap t0
            PREF_AF(afA, t0 + 2);
            PREF_BF(bfA);
            COMP(afB, bfB);       // tap t0+1
        }
        COMP(afA, bfA);           // tap 24

        __builtin_amdgcn_s_barrier();   // waves done with xs before next stage

        // ---- epilogue: leaky relu + store ----
        int h = h0 + wv;
        float* ob = out + ((size_t)b * COTOT_ + cobase) * HW2 + (size_t)h * HW_;
        #pragma unroll
        for (int mf = 0; mf < 4; ++mf) {
            #pragma unroll
            for (int nf = 0; nf < 4; ++nf) {
                #pragma unroll
                for (int r = 0; r < 16; ++r) {
                    int co = mf * 32 + (r & 3) + 8 * (r >> 2) + 4 * lhi;
                    int w  = nf * 32 + l31;
                    float v = acc[mf][nf][r];
                    v = (v >= 0.0f) ? v : 0.01f * v;
                    ob[(size_t)co * HW2 + w] = v;
                }
            }
        }
    }
}

extern "C" void kernel_launch(void* const* d_in, const int* in_sizes, int n_in,
                              void* d_out, int out_size, void* d_ws, size_t ws_size,
                              hipStream_t stream) {
    const float* x       = (const float*)d_in[0];
    const float* kernel  = (const float*)d_in[1];
    const float* relaxed = (const float*)d_in[2];
    float* out = (float*)d_out;

    unsigned short* xt = (unsigned short*)d_ws;   // 16*132*132*32*2 = 17,842,176 B
    unsigned short* wt = (unsigned short*)((char*)d_ws + (size_t)B_ * XTH * XTH * IC_ * 2);

    const int xtot = B_ * XTH * XTH;
    xform_kernel<<<(xtot + 255) / 256, 256, 0, stream>>>(x, xt);

    const int wtot = 25 * COTOT_ * IC_;
    build_w_kernel<<<(wtot + 255) / 256, 256, 0, stream>>>(kernel, relaxed, wt);

    dim3 grid(HW_ / 8, B_, COTOT_ / 128);
    conv_mfma_kernel<<<grid, 256, 0, stream>>>(xt, wt, out);
}

// Round 11
// 302.437 us; speedup vs baseline: 1.2370x; 1.0155x over previous
//
#include <hip/hip_runtime.h>
#include <hip/hip_bf16.h>
#include <math.h>

// Problem constants
#define B_   16
#define IC_  32
#define HW_  128
#define NF_  8
#define OC_  64
#define K_   5
#define GRP_ 8
#define COTOT_ (OC_ * GRP_)   // 512
#define XTH  132              // padded spatial (128 + 2*2)
#define TAPSTRIDE (COTOT_ * IC_)   // elements per tap in wt
#define XROWB (XTH * IC_ * 2)      // 8448 bytes per xs row
#define HW2  (HW_ * HW_)

typedef short  short8  __attribute__((ext_vector_type(8)));
typedef unsigned short ushort8 __attribute__((ext_vector_type(8)));
typedef float  f32x16  __attribute__((ext_vector_type(16)));

static __device__ inline unsigned short f2bf(float f) {
    unsigned u = __builtin_bit_cast(unsigned, f);
    unsigned r = (u + 0x7FFFu + ((u >> 16) & 1u)) >> 16;
    return (unsigned short)r;
}

// async global -> LDS, 16 bytes per lane (dest = uniform base + lane*16)
__device__ __forceinline__ void gload16(void* lds, const void* g) {
    __builtin_amdgcn_global_load_lds(
        (const __attribute__((address_space(1))) unsigned int*)g,
        (__attribute__((address_space(3))) unsigned int*)lds, 16, 0, 0);
}

// ---------------------------------------------------------------------------
// Kernel 1: x NCHW fp32 -> padded NHWC bf16   xt[b][hp][wp][ic]
// ---------------------------------------------------------------------------
__global__ __launch_bounds__(256) void xform_kernel(
    const float* __restrict__ x, unsigned short* __restrict__ xt) {
    int idx = blockIdx.x * blockDim.x + threadIdx.x;
    const int TOT = B_ * XTH * XTH;
    if (idx >= TOT) return;
    int wp = idx % XTH;
    int t  = idx / XTH;
    int hp = t % XTH;
    int b  = t / XTH;

    unsigned short vals[IC_];
    bool interior = (hp >= 2) && (hp < 2 + HW_) && (wp >= 2) && (wp < 2 + HW_);
    if (interior) {
        const float* xb = x + ((size_t)b * IC_) * HW2 + (hp - 2) * HW_ + (wp - 2);
        #pragma unroll
        for (int ic = 0; ic < IC_; ++ic)
            vals[ic] = f2bf(xb[(size_t)ic * HW2]);
    } else {
        #pragma unroll
        for (int ic = 0; ic < IC_; ++ic) vals[ic] = 0;
    }
    ushort8* dst = (ushort8*)(xt + (size_t)idx * IC_);
    #pragma unroll
    for (int c = 0; c < 4; ++c) {
        ushort8 v;
        #pragma unroll
        for (int j = 0; j < 8; ++j) v[j] = vals[c * 8 + j];
        dst[c] = v;
    }
}

// ---------------------------------------------------------------------------
// Kernel 2: rotated+mixed weights -> bf16, layout wt[tap25][co512][ic32]
// ---------------------------------------------------------------------------
__global__ __launch_bounds__(256) void build_w_kernel(
    const float* __restrict__ kern,
    const float* __restrict__ relaxed,
    unsigned short* __restrict__ wt) {
    int idx = blockIdx.x * blockDim.x + threadIdx.x;
    const int TOT = 25 * COTOT_ * IC_;
    if (idx >= TOT) return;
    int ic = idx & (IC_ - 1);
    int t  = idx >> 5;
    int co = t & (COTOT_ - 1);
    int e  = t >> 9;            // ky*5+kx
    int a  = co & (GRP_ - 1);
    int o  = co >> 3;
    int i  = e / K_;            // ky
    int j  = e - i * K_;        // kx

    float theta = -6.283185307179586f / (float)GRP_ * (float)a;
    float cth = cosf(theta), sth = sinf(theta);
    float bx = (2.0f * (float)j + 1.0f) / (float)K_ - 1.0f;
    float by = (2.0f * (float)i + 1.0f) / (float)K_ - 1.0f;
    float gx = cth * bx - sth * by;
    float gy = sth * bx + cth * by;
    float ix = ((gx + 1.0f) * (float)K_ - 1.0f) * 0.5f;
    float iy = ((gy + 1.0f) * (float)K_ - 1.0f) * 0.5f;
    float x0 = floorf(ix), y0 = floorf(iy);
    float wx1 = ix - x0, wy1 = iy - y0;
    float wx0 = 1.0f - wx1, wy0 = 1.0f - wy1;

    float xs2[2]  = {x0, x0 + 1.0f};
    float ys2[2]  = {y0, y0 + 1.0f};
    float wxs[2] = {wx0, wx1};
    float wys[2] = {wy0, wy1};

    float tw[4];
    int   tyc[4], txc[4];
    #pragma unroll
    for (int dy = 0; dy < 2; ++dy) {
        #pragma unroll
        for (int dx = 0; dx < 2; ++dx) {
            float xx = xs2[dx], yy = ys2[dy];
            bool valid = (xx >= 0.0f) && (xx < (float)K_) &&
                         (yy >= 0.0f) && (yy < (float)K_);
            int tp = dy * 2 + dx;
            tw[tp]  = wys[dy] * wxs[dx] * (valid ? 1.0f : 0.0f);
            txc[tp] = (int)fminf(fmaxf(xx, 0.0f), (float)(K_ - 1));
            tyc[tp] = (int)fminf(fmaxf(yy, 0.0f), (float)(K_ - 1));
        }
    }

    float acc = 0.0f;
    #pragma unroll
    for (int n = 0; n < NF_; ++n) {
        const float* kb = kern + ((size_t)((n * OC_ + o) * IC_ + ic)) * (K_ * K_);
        float v = 0.0f;
        #pragma unroll
        for (int tp = 0; tp < 4; ++tp)
            v += kb[tyc[tp] * K_ + txc[tp]] * tw[tp];
        acc += relaxed[n * GRP_ + a] * v;
    }
    wt[idx] = f2bf(acc);
}

// ---------------------------------------------------------------------------
// Kernel 3: MFMA implicit-GEMM conv + leaky relu  (32x32x16 MFMA)
// block = 256 thr (4 waves) = 128 co x 4 h x 128 w; 1 block/CU, 1 wave/SIMD
// wave  = 4x4 frags of 32x32: 128 co x 128 w at one h row, acc = 16xf32x16
// COMP is kk-OUTER: 16 independent MFMAs per half, no RAW-dependent
// neighbors (R10's kk-inner dependent pairs stalled the 32-cyc pipe).
// 2 slabs per block: amortizes prologue, overlaps store drain with compute.
// Weights: global -> VGPR (8 reads of 16B/tap), register double-buffer.
// x: swizzled LDS slab (conflict-free at 8-lane/128B grain), reg-dbuf reads.
// ---------------------------------------------------------------------------
#define PREF_AF(dst, tap) {                                                   \
    const unsigned short* wp_ = wl + (size_t)(tap) * TAPSTRIDE;               \
    _Pragma("unroll")                                                         \
    for (int mf = 0; mf < 4; ++mf)                                            \
        _Pragma("unroll")                                                     \
        for (int kk = 0; kk < 2; ++kk)                                        \
            dst[mf * 2 + kk] = *(const short8*)(wp_ + mf * 1024 + kk * 16);   \
}

#define PREF_BF(dst) {                                                        \
    int sw_ = ((pkx + l31) >> 1) & 3;                                         \
    int wb_ = prow + (pkx + l31) * 64;                                        \
    _Pragma("unroll")                                                         \
    for (int nf = 0; nf < 4; ++nf)                                            \
        _Pragma("unroll")                                                     \
        for (int kk = 0; kk < 2; ++kk) {                                      \
            int p_ = (kk * 2 + lhi) ^ sw_;                                    \
            dst[nf * 2 + kk] = *(const short8*)(xsb + wb_ + nf * 2048 + p_ * 16); \
        }                                                                     \
    if (++pkx == 5) { pkx = 0; prow += XROWB; }                               \
}

#define COMP(afx, bfx) {                                                      \
    __builtin_amdgcn_s_setprio(1);                                            \
    _Pragma("unroll")                                                         \
    for (int kk = 0; kk < 2; ++kk)                                            \
        _Pragma("unroll")                                                     \
        for (int mf = 0; mf < 4; ++mf)                                        \
            _Pragma("unroll")                                                 \
            for (int nf = 0; nf < 4; ++nf)                                    \
                acc[mf][nf] = __builtin_amdgcn_mfma_f32_32x32x16_bf16(        \
                    afx[mf * 2 + kk], bfx[nf * 2 + kk], acc[mf][nf], 0, 0, 0);\
    __builtin_amdgcn_s_setprio(0);                                            \
}

__global__ __launch_bounds__(256, 1) void conv_mfma_kernel(
    const unsigned short* __restrict__ xt,
    const unsigned short* __restrict__ wt,
    float* __restrict__ out) {
    // 8 rows x 132 w x 32 ic bf16 = 67584 B (chunk-swizzled via source)
    __shared__ __align__(16) unsigned short xs[8 * XTH * IC_];

    int tid  = threadIdx.x;
    int lane = tid & 63;
    int wv   = tid >> 6;          // 0..3 = wave's h row within slab
    int l31  = lane & 31;
    int lhi  = lane >> 5;         // 0/1 (k-half within 16-group: +8 ic)

    int hp = blockIdx.x;          // 0..15 -> two slabs of 4 rows
    int b  = blockIdx.y;
    int cg = blockIdx.z;          // 0..3, slowest
    int cobase = cg * 128;

    // per-lane weight base: co = cobase + mf*32 + l31, ic = kk*16 + lhi*8 ..
    const unsigned short* wl = wt + (size_t)(cobase + l31) * IC_ + lhi * 8;
    const char* xsb = (const char*)xs;

    #pragma unroll 1
    for (int s = 0; s < 2; ++s) {
        int h0 = hp * 8 + s * 4;

        if (s) __syncthreads();   // all waves done reading xs (prev slab)

        // ---- stage x slab rows h0..h0+7 (linear dest, swizzled source) ----
        {
            const unsigned short* xb = xt + (((size_t)b * XTH + h0) * XTH) * IC_;
            #pragma unroll
            for (int i = 0; i < 17; ++i) {
                int sl = i * 256 + tid;     // 16B slots, 4224 total
                if (sl < 4224) {
                    int row = sl / 528;
                    int rem = sl - row * 528;
                    int w   = rem >> 2;
                    int p   = rem & 3;
                    int c   = p ^ ((w >> 1) & 3);
                    gload16(&xs[sl * 8], xb + row * (XTH * IC_) + w * 32 + c * 8);
                }
            }
        }

        short8 afA[8], afB[8];
        PREF_AF(afA, 0);          // overlaps x staging

        f32x16 acc[4][4];
        #pragma unroll
        for (int mf = 0; mf < 4; ++mf)
            #pragma unroll
            for (int nf = 0; nf < 4; ++nf) acc[mf][nf] = (f32x16)(0.0f);

        __syncthreads();          // xs ready (drains vmcnt)

        int pkx  = 0;
        int prow = wv * XROWB;

        short8 bfA[8], bfB[8];
        PREF_BF(bfA);             // tap 0

        #pragma unroll 1
        for (int pi = 0; pi < 12; ++pi) {
            int t0 = pi * 2;
            PREF_AF(afB, t0 + 1);
            PREF_BF(bfB);
            COMP(afA, bfA);       // tap t0
            PREF_AF(afA, t0 + 2);
            PREF_BF(bfA);
            COMP(afB, bfB);       // tap t0+1
        }
        COMP(afA, bfA);           // tap 24

        __builtin_amdgcn_s_barrier();   // waves done with xs before next stage

        // ---- epilogue: leaky relu + store ----
        int h = h0 + wv;
        float* ob = out + ((size_t)b * COTOT_ + cobase) * HW2 + (size_t)h * HW_;
        #pragma unroll
        for (int mf = 0; mf < 4; ++mf) {
            #pragma unroll
            for (int nf = 0; nf < 4; ++nf) {
                #pragma unroll
                for (int r = 0; r < 16; ++r) {
                    int co = mf * 32 + (r & 3) + 8 * (r >> 2) + 4 * lhi;
                    int w  = nf * 32 + l31;
                    float v = acc[mf][nf][r];
                    v = (v >= 0.0f) ? v : 0.01f * v;
                    ob[(size_t)co * HW2 + w] = v;
                }
            }
        }
    }
}

extern "C" void kernel_launch(void* const* d_in, const int* in_sizes, int n_in,
                              void* d_out, int out_size, void* d_ws, size_t ws_size,
                              hipStream_t stream) {
    const float* x       = (const float*)d_in[0];
    const float* kernel  = (const float*)d_in[1];
    const float* relaxed = (const float*)d_in[2];
    float* out = (float*)d_out;

    unsigned short* xt = (unsigned short*)d_ws;   // 16*132*132*32*2 = 17,842,176 B
    unsigned short* wt = (unsigned short*)((char*)d_ws + (size_t)B_ * XTH * XTH * IC_ * 2);

    const int xtot = B_ * XTH * XTH;
    xform_kernel<<<(xtot + 255) / 256, 256, 0, stream>>>(x, xt);

    const int wtot = 25 * COTOT_ * IC_;
    build_w_kernel<<<(wtot + 255) / 256, 256, 0, stream>>>(kernel, relaxed, wt);

    dim3 grid(HW_ / 8, B_, COTOT_ / 128);
    conv_mfma_kernel<<<grid, 256, 0, stream>>>(xt, wt, out);
}